// Round 6
// baseline (736.949 us; speedup 1.0000x reference)
//
#include <hip/hip_runtime.h>
#include <math.h>

// Problem constants (B,C,T,H,W)=(4,3,12,256,256), CH0=32
#define HW_    65536
#define THW_   786432      // T*H*W
#define NP     262144      // B*H*W pixels
#define N1_    3145728.0   // B*T*H*W
#define N3_    262144.0    // B*H*W
#define NBLK   1024

// dws shard layout (doubles):
//   XB: x-stats, 9 quantities x 8 shards          [0,72)
//   SB: h-stats, 132 quantities x 8 shards        [72,1128)   q = o*4+{mn,mn2,mx,mx2}; 128..131 = Srt,SSrt,Stt,SStt
//   EB: enc-stats, 256 quantities x 4 shards      [1128,2152) q = b*64 + o*2 + {S,SS}
//   barrier counter at dws[DWN]
#define XB 0
#define SB 72
#define EB 1128
#define DWN 2152

// Ricker (K=5, a=1.25) and ramp weights
__device__ __constant__ float PW_[5] = {-0.33647654f, 0.20279402f, 0.77575913f, 0.20279402f, -0.33647654f};
__device__ __constant__ float RW_[5] = {-0.2f, -0.1f, 0.0f, 0.1f, 0.2f};

typedef __fp16 fp16x2 __attribute__((ext_vector_type(2)));
union H2U { fp16x2 h; unsigned int u; };
__device__ __forceinline__ unsigned int packh(float a, float b) {
  H2U x; x.h = __builtin_amdgcn_cvt_pkrtz(a, b); return x.u;
}
__device__ __forceinline__ float2 unpackh(unsigned int v) {
  H2U x; x.u = v; return make_float2((float)x.h.x, (float)x.h.y);
}

__device__ __forceinline__ float wred64(float v) {
#pragma unroll
  for (int m = 32; m > 0; m >>= 1) v += __shfl_xor(v, m, 64);
  return v;
}

__device__ __forceinline__ float fsilu(float y) {
  float e = __expf(-y);
  return y * __builtin_amdgcn_rcpf(1.0f + e);
}

// Inline grid barrier: monotonic counter, no function-call ABI.
__device__ __forceinline__ void gridbar(unsigned int* cnt, unsigned int target) {
  __syncthreads();
  if (threadIdx.x == 0) {
    __hip_atomic_fetch_add(cnt, 1u, __ATOMIC_ACQ_REL, __HIP_MEMORY_SCOPE_AGENT);
    while (__hip_atomic_load(cnt, __ATOMIC_ACQUIRE, __HIP_MEMORY_SCOPE_AGENT) < target) {
      __builtin_amdgcn_s_sleep(8);
    }
  }
  __syncthreads();
}

__device__ __forceinline__ double aload(const double* p) {
  return __hip_atomic_load(p, __ATOMIC_RELAXED, __HIP_MEMORY_SCOPE_AGENT);
}

__global__ void k_init(double* dws) {
  int i = blockIdx.x * 256 + threadIdx.x;
  if (i <= DWN) dws[i] = 0.0;   // includes barrier counter at dws[DWN]
}

// ================= cooperative mega-kernel =================
// Pin occupancy to exactly 4 waves/EU (16 waves/CU, 4 blocks/CU) so the
// register allocator budgets 128 VGPRs and does NOT spill to chase 8 waves/EU.
__global__ __launch_bounds__(256) __attribute__((amdgpu_waves_per_eu(4, 4)))
void k_mega(
    const float* __restrict__ x, const float* __restrict__ w0, const float* __restrict__ g0,
    const float* __restrict__ b0, const float* __restrict__ wrt, const float* __restrict__ grt,
    const float* __restrict__ brt, const float* __restrict__ wtt, const float* __restrict__ gtt,
    const float* __restrict__ btt, const float* __restrict__ wth, const float* __restrict__ bth,
    const float* __restrict__ gmin, const float* __restrict__ bmin, const float* __restrict__ gmax,
    const float* __restrict__ bmax, const float* __restrict__ gmean, const float* __restrict__ bmean,
    double* __restrict__ dws, float* __restrict__ out)
{
  unsigned int* bar = (unsigned int*)(dws + DWN);
  const int tid = threadIdx.x;
  const int bid = blockIdx.x;
  const int pix = bid * 256 + tid;
  const int b = bid >> 8;                 // uniform per block
  const int hw = pix & 65535;
  const int wave = tid >> 6, lane = tid & 63;

  __shared__ float red[4][132];
  __shared__ double sd[132];
  __shared__ double sum9[9];
  __shared__ float cfa0[32], cfa1[32], cfa2[32], cfb[32], lwrt[32];
  __shared__ float camn[32], cbmn[32], camx[32], cbmx[32], came[32], cbme[32];
  __shared__ float c4[4];
  __shared__ float lwth[384], lbth[32];
  __shared__ float lm[32], lr[32];

  // preload small tables
  for (int i = tid; i < 384; i += 256) lwth[i] = wth[i];
  if (tid < 32) { lbth[tid] = bth[tid]; lwrt[tid] = wrt[tid]; }

  // ---- load x column ----
  const float* xp = x + (size_t)b * 3 * THW_ + hw;
  float xv[3][12];
#pragma unroll
  for (int c = 0; c < 3; c++)
#pragma unroll
    for (int t = 0; t < 12; t++) xv[c][t] = xp[(size_t)(c * 12 + t) * HW_];

  // ---- P0: x statistics ----
  {
    float s0 = 0, s1 = 0, s2 = 0, p00 = 0, p01 = 0, p02 = 0, p11 = 0, p12 = 0, p22 = 0;
#pragma unroll
    for (int t = 0; t < 12; t++) {
      float a0 = xv[0][t], a1 = xv[1][t], a2 = xv[2][t];
      s0 += a0; s1 += a1; s2 += a2;
      p00 = fmaf(a0, a0, p00); p11 = fmaf(a1, a1, p11); p22 = fmaf(a2, a2, p22);
      p01 = fmaf(a0, a1, p01); p02 = fmaf(a0, a2, p02); p12 = fmaf(a1, a2, p12);
    }
    float vals[9] = {s0, s1, s2, p00, p01, p02, p11, p12, p22};
#pragma unroll
    for (int q = 0; q < 9; q++) vals[q] = wred64(vals[q]);
    if (lane == 0) {
#pragma unroll
      for (int q = 0; q < 9; q++) red[wave][q] = vals[q];
    }
    __syncthreads();
    if (tid < 9) {
      double v = (double)red[0][tid] + red[1][tid] + red[2][tid] + red[3][tid];
      atomicAdd(&dws[XB + tid * 8 + (bid & 7)], v);
    }
  }
  gridbar(bar, NBLK);

  // ---- P0b: derive bn0 constants into LDS ----
  if (tid < 9) {
    double t = 0;
#pragma unroll
    for (int s = 0; s < 8; s++) t += aload(&dws[XB + tid * 8 + s]);
    sum9[tid] = t;
  }
  __syncthreads();
  if (tid < 32) {
    int o = tid;
    double mu0 = sum9[0] / N1_, mu1 = sum9[1] / N1_, mu2 = sum9[2] / N1_;
    double M00 = sum9[3] / N1_, M01 = sum9[4] / N1_, M02 = sum9[5] / N1_;
    double M11 = sum9[6] / N1_, M12 = sum9[7] / N1_, M22 = sum9[8] / N1_;
    double c0 = w0[o * 3 + 0], c1 = w0[o * 3 + 1], c2 = w0[o * 3 + 2];
    double Ey = c0 * mu0 + c1 * mu1 + c2 * mu2;
    double Ey2 = c0 * c0 * M00 + c1 * c1 * M11 + c2 * c2 * M22 +
                 2.0 * (c0 * c1 * M01 + c0 * c2 * M02 + c1 * c2 * M12);
    double var = Ey2 - Ey * Ey;
    double alpha = (double)g0[o] / sqrt(var + 1e-5);
    cfa0[o] = (float)(alpha * c0);
    cfa1[o] = (float)(alpha * c1);
    cfa2[o] = (float)(alpha * c2);
    cfb[o] = (float)((double)b0[o] - Ey * alpha);
  }
  __syncthreads();

  // ---- P1: temporal conv (tt_pre) + h + per-o min/max + rt_pre, with stats ----
  float wt0 = wtt[0], wt1 = wtt[1], wt2 = wtt[2];
  float wtc[3] = {wt0, wt1, wt2};
  unsigned int tpk[6];
  float stt = 0.f, sstt = 0.f;
#pragma unroll
  for (int th = 0; th < 6; th++) {
    float tv[2];
#pragma unroll
    for (int k = 0; k < 2; k++) {
      int t = th * 2 + k;
      float acc = 0.f;
#pragma unroll
      for (int c = 0; c < 3; c++) {
        float pk = 0.f, sl = 0.f;
#pragma unroll
        for (int j = 0; j < 5; j++) {
          int tj = t - 2 + j;
          if (tj >= 0 && tj < 12) {
            pk = fmaf(PW_[j], xv[c][tj], pk);
            sl = fmaf(RW_[j], xv[c][tj], sl);
          }
        }
        acc = fmaf(wtc[c], pk + fabsf(sl), acc);
      }
      tv[k] = acc;
      stt += acc;
      sstt = fmaf(acc, acc, sstt);
    }
    tpk[th] = packh(tv[0], tv[1]);
  }

  float rt[12];
#pragma unroll
  for (int t = 0; t < 12; t++) rt[t] = 0.f;
  unsigned int pkmm[32];
#pragma unroll
  for (int o = 0; o < 32; o++) {
    float a0 = cfa0[o], a1 = cfa1[o], a2 = cfa2[o], bet = cfb[o], wo = lwrt[o];
    float mn = 3.4e38f, mx = -3.4e38f;
#pragma unroll
    for (int t = 0; t < 12; t++) {
      float y = fmaf(a0, xv[0][t], fmaf(a1, xv[1][t], fmaf(a2, xv[2][t], bet)));
      float h = fsilu(y);
      mn = fminf(mn, h);
      mx = fmaxf(mx, h);
      rt[t] = fmaf(wo, h, rt[t]);
    }
    pkmm[o] = packh(mn, mx);
    float q0 = wred64(mn), q1 = wred64(mn * mn), q2 = wred64(mx), q3 = wred64(mx * mx);
    if (lane == 0) {
      red[wave][o * 4 + 0] = q0;
      red[wave][o * 4 + 1] = q1;
      red[wave][o * 4 + 2] = q2;
      red[wave][o * 4 + 3] = q3;
    }
  }
  {
    float srt = 0.f, ssrt = 0.f;
#pragma unroll
    for (int t = 0; t < 12; t++) { srt += rt[t]; ssrt = fmaf(rt[t], rt[t], ssrt); }
    srt = wred64(srt); ssrt = wred64(ssrt);
    float s2 = wred64(stt), s3 = wred64(sstt);
    if (lane == 0) {
      red[wave][128] = srt; red[wave][129] = ssrt;
      red[wave][130] = s2;  red[wave][131] = s3;
    }
  }
  __syncthreads();
  if (tid < 132) {
    double v = (double)red[0][tid] + red[1][tid] + red[2][tid] + red[3][tid];
    atomicAdd(&dws[SB + tid * 8 + (bid & 7)], v);
  }
  gridbar(bar, 2 * NBLK);

  // ---- P2: derive remaining BN constants ----
  if (tid < 132) {
    double v = 0;
#pragma unroll
    for (int s = 0; s < 8; s++) v += aload(&dws[SB + tid * 8 + s]);
    sd[tid] = v;
  }
  __syncthreads();
  if (tid < 32) {
    int o = tid;
    double m = sd[o * 4 + 0] / N3_, v = sd[o * 4 + 1] / N3_ - m * m;
    double a = (double)gmin[o] / sqrt(v + 1e-5);
    camn[o] = (float)a; cbmn[o] = (float)((double)bmin[o] - m * a);
    m = sd[o * 4 + 2] / N3_; v = sd[o * 4 + 3] / N3_ - m * m;
    a = (double)gmax[o] / sqrt(v + 1e-5);
    camx[o] = (float)a; cbmx[o] = (float)((double)bmax[o] - m * a);
    a = (double)gmean[o] / sqrt(v + 1e-5);
    came[o] = (float)a; cbme[o] = (float)((double)bmean[o] - m * a);
  }
  if (tid == 32) {
    double m = sd[128] / N1_, v = sd[129] / N1_ - m * m;
    double a = (double)grt[0] / sqrt(v + 1e-5);
    c4[0] = (float)a; c4[1] = (float)((double)brt[0] - m * a);
    m = sd[130] / N1_; v = sd[131] / N1_ - m * m;
    a = (double)gtt[0] / sqrt(v + 1e-5);
    c4[2] = (float)a; c4[3] = (float)((double)btt[0] - m * a);
  }
  __syncthreads();

  // ---- P3: assemble enc in registers + per-slice sums ----
  float art = c4[0], brt_ = c4[1], att = c4[2], btt_ = c4[3];
  float rtt[12];
#pragma unroll
  for (int th = 0; th < 6; th++) {
    float2 tv = unpackh(tpk[th]);
    rtt[th * 2 + 0] = fsilu(fmaf(art, rt[th * 2 + 0], brt_)) + fsilu(fmaf(att, tv.x, btt_));
    rtt[th * 2 + 1] = fsilu(fmaf(art, rt[th * 2 + 1], brt_)) + fsilu(fmaf(att, tv.y, btt_));
  }
  float enc[32];
#pragma unroll
  for (int o = 0; o < 32; o++) {
    float2 mm = unpackh(pkmm[o]);
    float tl = lbth[o];
#pragma unroll
    for (int t = 0; t < 12; t++) tl = fmaf(lwth[o * 12 + t], rtt[t], tl);
    float e = tl + fsilu(fmaf(camn[o], mm.x, cbmn[o]))
                 + fsilu(fmaf(camx[o], mm.y, cbmx[o]))
                 + fsilu(fmaf(came[o], mm.y, cbme[o]));
    enc[o] = e;
    float se = wred64(e), se2 = wred64(e * e);
    if (lane == 0) { red[wave][o * 2 + 0] = se; red[wave][o * 2 + 1] = se2; }
  }
  __syncthreads();
  if (tid < 64) {
    double v = (double)red[0][tid] + red[1][tid] + red[2][tid] + red[3][tid];
    atomicAdd(&dws[EB + (b * 64 + tid) * 4 + (bid & 3)], v);
  }
  gridbar(bar, 3 * NBLK);

  // ---- P4: instance norm from registers ----
  if (tid < 64) {
    double v = 0;
#pragma unroll
    for (int s = 0; s < 4; s++) v += aload(&dws[EB + (b * 64 + tid) * 4 + s]);
    sd[tid] = v;
  }
  __syncthreads();
  if (tid < 32) {
    double m = sd[tid * 2] / 65536.0, var = sd[tid * 2 + 1] / 65536.0 - m * m;
    lm[tid] = (float)m;
    lr[tid] = (float)(1.0 / sqrt(var + 1e-5));
  }
  __syncthreads();
  float* po = out + ((size_t)(b * 32) << 16) + hw;
#pragma unroll
  for (int o = 0; o < 32; o++) po[(size_t)o << 16] = (enc[o] - lm[o]) * lr[o];
}

// ================= fallback path (round-3 pipeline) =================
__global__ __launch_bounds__(256) void k_xstats(const float* __restrict__ x, double* __restrict__ dws) {
  const int v = blockIdx.x * 256 + threadIdx.x;
  const float4* x4 = (const float4*)x;
  float s0 = 0, s1 = 0, s2 = 0, p00 = 0, p01 = 0, p02 = 0, p11 = 0, p12 = 0, p22 = 0;
#pragma unroll
  for (int b = 0; b < 4; b++) {
    float4 a0 = x4[(size_t)(b * 3 + 0) * 196608 + v];
    float4 a1 = x4[(size_t)(b * 3 + 1) * 196608 + v];
    float4 a2 = x4[(size_t)(b * 3 + 2) * 196608 + v];
    s0 += a0.x + a0.y + a0.z + a0.w;
    s1 += a1.x + a1.y + a1.z + a1.w;
    s2 += a2.x + a2.y + a2.z + a2.w;
    p00 += a0.x * a0.x + a0.y * a0.y + a0.z * a0.z + a0.w * a0.w;
    p11 += a1.x * a1.x + a1.y * a1.y + a1.z * a1.z + a1.w * a1.w;
    p22 += a2.x * a2.x + a2.y * a2.y + a2.z * a2.z + a2.w * a2.w;
    p01 += a0.x * a1.x + a0.y * a1.y + a0.z * a1.z + a0.w * a1.w;
    p02 += a0.x * a2.x + a0.y * a2.y + a0.z * a2.z + a0.w * a2.w;
    p12 += a1.x * a2.x + a1.y * a2.y + a1.z * a2.z + a1.w * a2.w;
  }
  float vals[9] = {s0, s1, s2, p00, p01, p02, p11, p12, p22};
  __shared__ float red[4][9];
  int wave = threadIdx.x >> 6, lane = threadIdx.x & 63;
#pragma unroll
  for (int q = 0; q < 9; q++) vals[q] = wred64(vals[q]);
  if (lane == 0) {
#pragma unroll
    for (int q = 0; q < 9; q++) red[wave][q] = vals[q];
  }
  __syncthreads();
  if (threadIdx.x < 9) {
    double t = (double)red[0][threadIdx.x] + red[1][threadIdx.x] + red[2][threadIdx.x] + red[3][threadIdx.x];
    atomicAdd(&dws[XB + threadIdx.x * 8], t);
  }
}

__global__ void k_fin0(const double* __restrict__ dws, const float* __restrict__ w0,
                       const float* __restrict__ g0, const float* __restrict__ b0, float* __restrict__ cf) {
  int o = threadIdx.x;
  if (o >= 32) return;
  double mu0 = dws[XB + 0 * 8] / N1_, mu1 = dws[XB + 1 * 8] / N1_, mu2 = dws[XB + 2 * 8] / N1_;
  double M00 = dws[XB + 3 * 8] / N1_, M01 = dws[XB + 4 * 8] / N1_, M02 = dws[XB + 5 * 8] / N1_;
  double M11 = dws[XB + 6 * 8] / N1_, M12 = dws[XB + 7 * 8] / N1_, M22 = dws[XB + 8 * 8] / N1_;
  double c0 = w0[o * 3 + 0], c1 = w0[o * 3 + 1], c2 = w0[o * 3 + 2];
  double Ey = c0 * mu0 + c1 * mu1 + c2 * mu2;
  double Ey2 = c0 * c0 * M00 + c1 * c1 * M11 + c2 * c2 * M22 +
               2.0 * (c0 * c1 * M01 + c0 * c2 * M02 + c1 * c2 * M12);
  double var = Ey2 - Ey * Ey;
  double alpha = (double)g0[o] / sqrt(var + 1e-5);
  cf[o * 3 + 0] = (float)(alpha * c0);
  cf[o * 3 + 1] = (float)(alpha * c1);
  cf[o * 3 + 2] = (float)(alpha * c2);
  cf[96 + o] = (float)((double)b0[o] - Ey * alpha);
}

__global__ __launch_bounds__(256) void k_passB(const float* __restrict__ x, const float* __restrict__ wrt,
                                               const float* __restrict__ wtt, const float* __restrict__ cf,
                                               unsigned int* __restrict__ pRT, unsigned int* __restrict__ pMM) {
  const int pix = blockIdx.x * 256 + threadIdx.x;
  const int b = pix >> 16, hw = pix & 65535;
  const float* xp = x + (size_t)b * 3 * THW_ + hw;
  float xv[3][12];
#pragma unroll
  for (int c = 0; c < 3; c++)
#pragma unroll
    for (int t = 0; t < 12; t++) xv[c][t] = xp[(size_t)(c * 12 + t) * HW_];
  float wt[3] = {wtt[0], wtt[1], wtt[2]};
  float ttp[12];
#pragma unroll
  for (int t = 0; t < 12; t++) {
    float acc = 0.f;
#pragma unroll
    for (int c = 0; c < 3; c++) {
      float pk = 0.f, sl = 0.f;
#pragma unroll
      for (int j = 0; j < 5; j++) {
        int tj = t - 2 + j;
        if (tj >= 0 && tj < 12) {
          pk = fmaf(PW_[j], xv[c][tj], pk);
          sl = fmaf(RW_[j], xv[c][tj], sl);
        }
      }
      acc = fmaf(wt[c], pk + fabsf(sl), acc);
    }
    ttp[t] = acc;
  }
  float rt_t[12];
#pragma unroll
  for (int t = 0; t < 12; t++) rt_t[t] = 0.f;
#pragma unroll
  for (int o = 0; o < 32; o++) {
    float a0 = cf[o * 3], a1 = cf[o * 3 + 1], a2 = cf[o * 3 + 2];
    float bet = cf[96 + o], wo = wrt[o];
    float mn = 3.4e38f, mx = -3.4e38f;
#pragma unroll
    for (int t = 0; t < 12; t++) {
      float y = fmaf(a0, xv[0][t], fmaf(a1, xv[1][t], fmaf(a2, xv[2][t], bet)));
      float h = fsilu(y);
      mn = fminf(mn, h);
      mx = fmaxf(mx, h);
      rt_t[t] = fmaf(wo, h, rt_t[t]);
    }
    pMM[o * NP + pix] = packh(mn, mx);
  }
#pragma unroll
  for (int t = 0; t < 12; t++) pRT[t * NP + pix] = packh(rt_t[t], ttp[t]);
}

__global__ __launch_bounds__(256) void k_stats(const unsigned int* __restrict__ pRT,
                                               const unsigned int* __restrict__ pMM,
                                               double* __restrict__ dws) {
  __shared__ float red[4][4];
  int bid = blockIdx.x, tid = threadIdx.x;
  float s0 = 0, s1 = 0, s2 = 0, s3 = 0;
  if (bid < 96) {
    const uint4* p = (const uint4*)pRT;
    int base = bid * 256 + tid;
#pragma unroll 4
    for (int it = 0; it < 32; it++) {
      uint4 v = p[base + it * 24576];
      float2 a = unpackh(v.x), b = unpackh(v.y), c = unpackh(v.z), d = unpackh(v.w);
      s0 += a.x + b.x + c.x + d.x;
      s1 += a.x * a.x + b.x * b.x + c.x * c.x + d.x * d.x;
      s2 += a.y + b.y + c.y + d.y;
      s3 += a.y * a.y + b.y * b.y + c.y * c.y + d.y * d.y;
    }
  } else {
    int o = (bid - 96) >> 3, sub = (bid - 96) & 7;
    const uint4* p = (const uint4*)(pMM + (size_t)o * NP);
    int base = sub * 256 + tid;
#pragma unroll 4
    for (int it = 0; it < 32; it++) {
      uint4 v = p[base + it * 2048];
      float2 a = unpackh(v.x), b = unpackh(v.y), c = unpackh(v.z), d = unpackh(v.w);
      s0 += a.x + b.x + c.x + d.x;
      s1 += a.x * a.x + b.x * b.x + c.x * c.x + d.x * d.x;
      s2 += a.y + b.y + c.y + d.y;
      s3 += a.y * a.y + b.y * b.y + c.y * c.y + d.y * d.y;
    }
  }
  s0 = wred64(s0); s1 = wred64(s1); s2 = wred64(s2); s3 = wred64(s3);
  int wave = tid >> 6, lane = tid & 63;
  if (lane == 0) { red[wave][0] = s0; red[wave][1] = s1; red[wave][2] = s2; red[wave][3] = s3; }
  __syncthreads();
  if (tid < 4) {
    double v = (double)red[0][tid] + red[1][tid] + red[2][tid] + red[3][tid];
    if (bid < 96) atomicAdd(&dws[SB + (128 + tid) * 8], v);
    else { int o = (bid - 96) >> 3; atomicAdd(&dws[SB + (o * 4 + tid) * 8], v); }
  }
}

__global__ void k_finB(const double* __restrict__ dws, const float* __restrict__ grt, const float* __restrict__ brt,
                       const float* __restrict__ gtt, const float* __restrict__ btt, const float* __restrict__ gmin,
                       const float* __restrict__ bmin, const float* __restrict__ gmax, const float* __restrict__ bmax,
                       const float* __restrict__ gmean, const float* __restrict__ bmean, float* __restrict__ cf) {
  int tid = threadIdx.x;
  if (tid == 32) {
    double m = dws[SB + 128 * 8] / N1_, v = dws[SB + 129 * 8] / N1_ - m * m;
    double a = (double)grt[0] / sqrt(v + 1e-5);
    cf[128] = (float)a;
    cf[129] = (float)((double)brt[0] - m * a);
    m = dws[SB + 130 * 8] / N1_;
    v = dws[SB + 131 * 8] / N1_ - m * m;
    a = (double)gtt[0] / sqrt(v + 1e-5);
    cf[130] = (float)a;
    cf[131] = (float)((double)btt[0] - m * a);
  }
  if (tid < 32) {
    double m = dws[SB + (tid * 4 + 0) * 8] / N3_, v = dws[SB + (tid * 4 + 1) * 8] / N3_ - m * m;
    double a = (double)gmin[tid] / sqrt(v + 1e-5);
    cf[132 + tid] = (float)a;
    cf[164 + tid] = (float)((double)bmin[tid] - m * a);
    double mm = dws[SB + (tid * 4 + 2) * 8] / N3_, vv = dws[SB + (tid * 4 + 3) * 8] / N3_ - mm * mm;
    a = (double)gmax[tid] / sqrt(vv + 1e-5);
    cf[196 + tid] = (float)a;
    cf[228 + tid] = (float)((double)bmax[tid] - mm * a);
    a = (double)gmean[tid] / sqrt(vv + 1e-5);
    cf[260 + tid] = (float)a;
    cf[292 + tid] = (float)((double)bmean[tid] - mm * a);
  }
}

__global__ __launch_bounds__(256) void k_passC(const unsigned int* __restrict__ pRT,
                                               const unsigned int* __restrict__ pMM,
                                               const float* __restrict__ wth, const float* __restrict__ bth,
                                               const float* __restrict__ cf, float* __restrict__ out) {
  const int pix = blockIdx.x * 256 + threadIdx.x;
  const int b = pix >> 16, hw = pix & 65535;
  float art = cf[128], brt_ = cf[129], att = cf[130], btt_ = cf[131];
  float rtt[12];
#pragma unroll
  for (int t = 0; t < 12; t++) {
    float2 v = unpackh(pRT[t * NP + pix]);
    rtt[t] = fsilu(fmaf(art, v.x, brt_)) + fsilu(fmaf(att, v.y, btt_));
  }
  float* po = out + (size_t)b * 32 * HW_ + hw;
#pragma unroll
  for (int o = 0; o < 32; o++) {
    float2 mm = unpackh(pMM[o * NP + pix]);
    float tl = bth[o];
#pragma unroll
    for (int t = 0; t < 12; t++) tl = fmaf(wth[o * 12 + t], rtt[t], tl);
    float e = tl + fsilu(fmaf(cf[132 + o], mm.x, cf[164 + o]))
                 + fsilu(fmaf(cf[196 + o], mm.y, cf[228 + o]))
                 + fsilu(fmaf(cf[260 + o], mm.y, cf[292 + o]));
    po[(size_t)o * HW_] = e;
  }
}

__global__ __launch_bounds__(256) void k_encstats(const float* __restrict__ out, double* __restrict__ dws) {
  __shared__ float red[4][2];
  int s = blockIdx.x >> 2, sub = blockIdx.x & 3, tid = threadIdx.x;
  const float4* p = (const float4*)(out + ((size_t)s << 16));
  float S = 0, SS = 0;
#pragma unroll 4
  for (int it = 0; it < 16; it++) {
    float4 a = p[sub * 256 + tid + it * 1024];
    S += a.x + a.y + a.z + a.w;
    SS += a.x * a.x + a.y * a.y + a.z * a.z + a.w * a.w;
  }
  S = wred64(S); SS = wred64(SS);
  int wave = tid >> 6, lane = tid & 63;
  if (lane == 0) { red[wave][0] = S; red[wave][1] = SS; }
  __syncthreads();
  if (tid < 2) {
    double v = (double)red[0][tid] + red[1][tid] + red[2][tid] + red[3][tid];
    atomicAdd(&dws[EB + (s * 2 + tid) * 4], v);
  }
}

__global__ __launch_bounds__(256) void k_inorm(const double* __restrict__ dws, float* __restrict__ out) {
  int s = blockIdx.y;
  double S = dws[EB + s * 2 * 4], SS = dws[EB + (s * 2 + 1) * 4];
  double m = S / 65536.0, v = SS / 65536.0 - m * m;
  float rstd = (float)(1.0 / sqrt(v + 1e-5));
  float mf = (float)m;
  float4* p = (float4*)(out + ((size_t)s << 16));
  int i = blockIdx.x * 256 + threadIdx.x;
  float4 a = p[i];
  a.x = (a.x - mf) * rstd;
  a.y = (a.y - mf) * rstd;
  a.z = (a.z - mf) * rstd;
  a.w = (a.w - mf) * rstd;
  p[i] = a;
}

extern "C" void kernel_launch(void* const* d_in, const int* in_sizes, int n_in,
                              void* d_out, int out_size, void* d_ws, size_t ws_size,
                              hipStream_t stream) {
  const float* x     = (const float*)d_in[0];
  const float* w0    = (const float*)d_in[1];
  const float* g0    = (const float*)d_in[2];
  const float* b0    = (const float*)d_in[3];
  const float* wrt   = (const float*)d_in[4];
  const float* grt   = (const float*)d_in[5];
  const float* brt   = (const float*)d_in[6];
  const float* wtt   = (const float*)d_in[7];
  const float* gtt   = (const float*)d_in[8];
  const float* btt   = (const float*)d_in[9];
  const float* wth   = (const float*)d_in[10];
  const float* bth   = (const float*)d_in[11];
  const float* gmin  = (const float*)d_in[12];
  const float* bmin  = (const float*)d_in[13];
  const float* gmax  = (const float*)d_in[14];
  const float* bmax  = (const float*)d_in[15];
  const float* gmean = (const float*)d_in[16];
  const float* bmean = (const float*)d_in[17];
  double* dws = (double*)d_ws;
  float* out = (float*)d_out;

  hipLaunchKernelGGL(k_init, dim3(9), dim3(256), 0, stream, dws);

  void* args[] = {(void*)&x, (void*)&w0, (void*)&g0, (void*)&b0, (void*)&wrt, (void*)&grt,
                  (void*)&brt, (void*)&wtt, (void*)&gtt, (void*)&btt, (void*)&wth, (void*)&bth,
                  (void*)&gmin, (void*)&bmin, (void*)&gmax, (void*)&bmax, (void*)&gmean,
                  (void*)&bmean, (void*)&dws, (void*)&out};
  hipError_t e = hipLaunchCooperativeKernel((const void*)k_mega, dim3(NBLK), dim3(256),
                                            args, 0, stream);
  if (e == hipSuccess) return;

  // ---------- fallback: round-3 multi-kernel pipeline ----------
  float* cf = (float*)((char*)d_ws + 32768);
  unsigned int* pRT = (unsigned int*)((char*)d_ws + 65536);
  unsigned int* pMM = pRT + 12 * NP;
  hipLaunchKernelGGL(k_xstats, dim3(768), dim3(256), 0, stream, x, dws);
  hipLaunchKernelGGL(k_fin0, dim3(1), dim3(32), 0, stream, dws, w0, g0, b0, cf);
  hipLaunchKernelGGL(k_passB, dim3(1024), dim3(256), 0, stream, x, wrt, wtt, cf, pRT, pMM);
  hipLaunchKernelGGL(k_stats, dim3(352), dim3(256), 0, stream, pRT, pMM, dws);
  hipLaunchKernelGGL(k_finB, dim3(1), dim3(64), 0, stream, dws, grt, brt, gtt, btt,
                     gmin, bmin, gmax, bmax, gmean, bmean, cf);
  hipLaunchKernelGGL(k_passC, dim3(1024), dim3(256), 0, stream, pRT, pMM, wth, bth, cf, out);
  hipLaunchKernelGGL(k_encstats, dim3(512), dim3(256), 0, stream, out, dws);
  hipLaunchKernelGGL(k_inorm, dim3(64, 128), dim3(256), 0, stream, dws, out);
}

// Round 8
// 145.919 us; speedup vs baseline: 5.0504x; 5.0504x over previous
//
#include <hip/hip_runtime.h>
#include <math.h>

// Problem constants (B,C,T,H,W)=(4,3,12,256,256), CH0=32
#define HW_    65536
#define THW_   786432      // T*H*W
#define NP     262144      // B*H*W pixels
#define N1_    3145728.0   // B*T*H*W
#define N3_    262144.0    // B*H*W

// dws shard layout (doubles):
//   XB: x-stats, 9 quantities x 8 shards          [0,72)
//   SB: h-stats, 132 quantities x 8 shards        [72,1128)   q = o*4+{mn,mn2,mx,mx2}; 128..131 = Srt,SSrt,Stt,SStt
//   EB: enc-stats, 256 quantities x 4 shards      [1128,2152) q = (b*32+o)*2 + {S,SS}
#define XB 0
#define SB 72
#define EB 1128
#define DWN 2152

__device__ __constant__ float PW_[5] = {-0.33647654f, 0.20279402f, 0.77575913f, 0.20279402f, -0.33647654f};
__device__ __constant__ float RW_[5] = {-0.2f, -0.1f, 0.0f, 0.1f, 0.2f};

typedef __fp16 fp16x2 __attribute__((ext_vector_type(2)));
union H2U { fp16x2 h; unsigned int u; };
__device__ __forceinline__ unsigned int packh(float a, float b) {
  H2U x; x.h = __builtin_amdgcn_cvt_pkrtz(a, b); return x.u;
}
__device__ __forceinline__ float2 unpackh(unsigned int v) {
  H2U x; x.u = v; return make_float2((float)x.h.x, (float)x.h.y);
}

__device__ __forceinline__ float wred64(float v) {
#pragma unroll
  for (int m = 32; m > 0; m >>= 1) v += __shfl_xor(v, m, 64);
  return v;
}

__device__ __forceinline__ float fsilu(float y) {
  float e = __expf(-y);
  return y * __builtin_amdgcn_rcpf(1.0f + e);
}

__global__ void k_init(double* dws) {
  int i = blockIdx.x * 256 + threadIdx.x;
  if (i < DWN) dws[i] = 0.0;
}

__global__ __launch_bounds__(256) void k_xstats(const float* __restrict__ x, double* __restrict__ dws) {
  const int v = blockIdx.x * 256 + threadIdx.x;   // float4 index in [0,196608)
  const float4* x4 = (const float4*)x;
  float s0 = 0, s1 = 0, s2 = 0, p00 = 0, p01 = 0, p02 = 0, p11 = 0, p12 = 0, p22 = 0;
#pragma unroll
  for (int b = 0; b < 4; b++) {
    float4 a0 = x4[(size_t)(b * 3 + 0) * 196608 + v];
    float4 a1 = x4[(size_t)(b * 3 + 1) * 196608 + v];
    float4 a2 = x4[(size_t)(b * 3 + 2) * 196608 + v];
    s0 += a0.x + a0.y + a0.z + a0.w;
    s1 += a1.x + a1.y + a1.z + a1.w;
    s2 += a2.x + a2.y + a2.z + a2.w;
    p00 += a0.x * a0.x + a0.y * a0.y + a0.z * a0.z + a0.w * a0.w;
    p11 += a1.x * a1.x + a1.y * a1.y + a1.z * a1.z + a1.w * a1.w;
    p22 += a2.x * a2.x + a2.y * a2.y + a2.z * a2.z + a2.w * a2.w;
    p01 += a0.x * a1.x + a0.y * a1.y + a0.z * a1.z + a0.w * a1.w;
    p02 += a0.x * a2.x + a0.y * a2.y + a0.z * a2.z + a0.w * a2.w;
    p12 += a1.x * a2.x + a1.y * a2.y + a1.z * a2.z + a1.w * a2.w;
  }
  float vals[9] = {s0, s1, s2, p00, p01, p02, p11, p12, p22};
  __shared__ float red[4][9];
  int wave = threadIdx.x >> 6, lane = threadIdx.x & 63;
#pragma unroll
  for (int q = 0; q < 9; q++) vals[q] = wred64(vals[q]);
  if (lane == 0) {
#pragma unroll
    for (int q = 0; q < 9; q++) red[wave][q] = vals[q];
  }
  __syncthreads();
  if (threadIdx.x < 9) {
    double t = (double)red[0][threadIdx.x] + red[1][threadIdx.x] + red[2][threadIdx.x] + red[3][threadIdx.x];
    atomicAdd(&dws[XB + threadIdx.x * 8 + (blockIdx.x & 7)], t);
  }
}

__global__ void k_fin0(const double* __restrict__ dws, const float* __restrict__ w0,
                       const float* __restrict__ g0, const float* __restrict__ b0, float* __restrict__ cf) {
  int o = threadIdx.x;
  if (o >= 32) return;
  double q[9];
#pragma unroll
  for (int i = 0; i < 9; i++) {
    double t = 0;
#pragma unroll
    for (int s = 0; s < 8; s++) t += dws[XB + i * 8 + s];
    q[i] = t / N1_;
  }
  double mu0 = q[0], mu1 = q[1], mu2 = q[2];
  double M00 = q[3], M01 = q[4], M02 = q[5], M11 = q[6], M12 = q[7], M22 = q[8];
  double c0 = w0[o * 3 + 0], c1 = w0[o * 3 + 1], c2 = w0[o * 3 + 2];
  double Ey = c0 * mu0 + c1 * mu1 + c2 * mu2;
  double Ey2 = c0 * c0 * M00 + c1 * c1 * M11 + c2 * c2 * M22 +
               2.0 * (c0 * c1 * M01 + c0 * c2 * M02 + c1 * c2 * M12);
  double var = Ey2 - Ey * Ey;
  double alpha = (double)g0[o] / sqrt(var + 1e-5);
  cf[o * 3 + 0] = (float)(alpha * c0);
  cf[o * 3 + 1] = (float)(alpha * c1);
  cf[o * 3 + 2] = (float)(alpha * c2);
  cf[96 + o] = (float)((double)b0[o] - Ey * alpha);
}

// passB: compute h once; stream fp16 intermediates; fused block-level h-stats
// via LDS-transpose reduce (stride 264 words => 8-lane-group reads are 2/bank).
__global__ __launch_bounds__(256) void k_passB(const float* __restrict__ x, const float* __restrict__ wrt,
                                               const float* __restrict__ wtt, const float* __restrict__ cf,
                                               unsigned int* __restrict__ pRT, unsigned int* __restrict__ pMM,
                                               double* __restrict__ dws) {
  const int tid = threadIdx.x;
  const int pix = blockIdx.x * 256 + tid;
  const int b = pix >> 16, hw = pix & 65535;
  __shared__ unsigned int lmm[32 * 264];
  __shared__ float red[4][4];
  const float* xp = x + (size_t)b * 3 * THW_ + hw;
  float xv[3][12];
#pragma unroll
  for (int c = 0; c < 3; c++)
#pragma unroll
    for (int t = 0; t < 12; t++) xv[c][t] = xp[(size_t)(c * 12 + t) * HW_];
  float wt[3] = {wtt[0], wtt[1], wtt[2]};
  float ttp[12];
#pragma unroll
  for (int t = 0; t < 12; t++) {
    float acc = 0.f;
#pragma unroll
    for (int c = 0; c < 3; c++) {
      float pk = 0.f, sl = 0.f;
#pragma unroll
      for (int j = 0; j < 5; j++) {
        int tj = t - 2 + j;
        if (tj >= 0 && tj < 12) {
          pk = fmaf(PW_[j], xv[c][tj], pk);
          sl = fmaf(RW_[j], xv[c][tj], sl);
        }
      }
      acc = fmaf(wt[c], pk + fabsf(sl), acc);
    }
    ttp[t] = acc;
  }
  float rt_t[12];
#pragma unroll
  for (int t = 0; t < 12; t++) rt_t[t] = 0.f;
#pragma unroll
  for (int o = 0; o < 32; o++) {
    float a0 = cf[o * 3], a1 = cf[o * 3 + 1], a2 = cf[o * 3 + 2];
    float bet = cf[96 + o], wo = wrt[o];
    float mn = 3.4e38f, mx = -3.4e38f;
#pragma unroll
    for (int t = 0; t < 12; t++) {
      float y = fmaf(a0, xv[0][t], fmaf(a1, xv[1][t], fmaf(a2, xv[2][t], bet)));
      float h = fsilu(y);
      mn = fminf(mn, h);
      mx = fmaxf(mx, h);
      rt_t[t] = fmaf(wo, h, rt_t[t]);
    }
    unsigned int pk = packh(mn, mx);
    pMM[o * NP + pix] = pk;
    lmm[o * 264 + tid] = pk;
  }
#pragma unroll
  for (int t = 0; t < 12; t++) pRT[t * NP + pix] = packh(rt_t[t], ttp[t]);

  // rt/tt scalar stats (4 wred64)
  {
    float srt = 0.f, ssrt = 0.f, stt = 0.f, sstt = 0.f;
#pragma unroll
    for (int t = 0; t < 12; t++) {
      srt += rt_t[t];  ssrt = fmaf(rt_t[t], rt_t[t], ssrt);
      stt += ttp[t];   sstt = fmaf(ttp[t], ttp[t], sstt);
    }
    srt = wred64(srt); ssrt = wred64(ssrt); stt = wred64(stt); sstt = wred64(sstt);
    int wave = tid >> 6, lane = tid & 63;
    if (lane == 0) { red[wave][0] = srt; red[wave][1] = ssrt; red[wave][2] = stt; red[wave][3] = sstt; }
  }
  __syncthreads();
  if (tid < 4) {
    double v = (double)red[0][tid] + red[1][tid] + red[2][tid] + red[3][tid];
    atomicAdd(&dws[SB + (128 + tid) * 8 + (blockIdx.x & 7)], v);
  }
  // per-o min/max stats: 8 threads per o scan 32 entries each
  {
    int o = tid >> 3, j = tid & 7;
    float smn = 0, smn2 = 0, smx = 0, smx2 = 0;
#pragma unroll
    for (int k = 0; k < 32; k++) {
      float2 mm = unpackh(lmm[o * 264 + j + k * 8]);
      smn += mm.x; smn2 = fmaf(mm.x, mm.x, smn2);
      smx += mm.y; smx2 = fmaf(mm.y, mm.y, smx2);
    }
#pragma unroll
    for (int m = 1; m < 8; m <<= 1) {
      smn  += __shfl_xor(smn, m, 64);
      smn2 += __shfl_xor(smn2, m, 64);
      smx  += __shfl_xor(smx, m, 64);
      smx2 += __shfl_xor(smx2, m, 64);
    }
    if (j == 0) {
      int sh = blockIdx.x & 7;
      atomicAdd(&dws[SB + (o * 4 + 0) * 8 + sh], (double)smn);
      atomicAdd(&dws[SB + (o * 4 + 1) * 8 + sh], (double)smn2);
      atomicAdd(&dws[SB + (o * 4 + 2) * 8 + sh], (double)smx);
      atomicAdd(&dws[SB + (o * 4 + 3) * 8 + sh], (double)smx2);
    }
  }
}

__global__ void k_finB(const double* __restrict__ dws, const float* __restrict__ grt, const float* __restrict__ brt,
                       const float* __restrict__ gtt, const float* __restrict__ btt, const float* __restrict__ gmin,
                       const float* __restrict__ bmin, const float* __restrict__ gmax, const float* __restrict__ bmax,
                       const float* __restrict__ gmean, const float* __restrict__ bmean, float* __restrict__ cf) {
  int tid = threadIdx.x;
  if (tid == 32) {
    double q[4];
#pragma unroll
    for (int i = 0; i < 4; i++) {
      double t = 0;
#pragma unroll
      for (int s = 0; s < 8; s++) t += dws[SB + (128 + i) * 8 + s];
      q[i] = t / N1_;
    }
    double m = q[0], v = q[1] - m * m;
    double a = (double)grt[0] / sqrt(v + 1e-5);
    cf[128] = (float)a;
    cf[129] = (float)((double)brt[0] - m * a);
    m = q[2]; v = q[3] - m * m;
    a = (double)gtt[0] / sqrt(v + 1e-5);
    cf[130] = (float)a;
    cf[131] = (float)((double)btt[0] - m * a);
  }
  if (tid < 32) {
    double q[4];
#pragma unroll
    for (int i = 0; i < 4; i++) {
      double t = 0;
#pragma unroll
      for (int s = 0; s < 8; s++) t += dws[SB + (tid * 4 + i) * 8 + s];
      q[i] = t / N3_;
    }
    double m = q[0], v = q[1] - m * m;
    double a = (double)gmin[tid] / sqrt(v + 1e-5);
    cf[132 + tid] = (float)a;
    cf[164 + tid] = (float)((double)bmin[tid] - m * a);
    double mm = q[2], vv = q[3] - mm * mm;
    a = (double)gmax[tid] / sqrt(vv + 1e-5);
    cf[196 + tid] = (float)a;
    cf[228 + tid] = (float)((double)bmax[tid] - mm * a);
    a = (double)gmean[tid] / sqrt(vv + 1e-5);
    cf[260 + tid] = (float)a;
    cf[292 + tid] = (float)((double)bmean[tid] - mm * a);
  }
}

// passC: read intermediates, assemble enc, write out; fused enc-stats via
// LDS-transpose reduce.
__global__ __launch_bounds__(256) void k_passC(const unsigned int* __restrict__ pRT,
                                               const unsigned int* __restrict__ pMM,
                                               const float* __restrict__ wth, const float* __restrict__ bth,
                                               const float* __restrict__ cf, float* __restrict__ out,
                                               double* __restrict__ dws) {
  const int tid = threadIdx.x;
  const int pix = blockIdx.x * 256 + tid;
  const int b = pix >> 16, hw = pix & 65535;
  __shared__ float lenc[32 * 264];
  float art = cf[128], brt_ = cf[129], att = cf[130], btt_ = cf[131];
  float rtt[12];
#pragma unroll
  for (int t = 0; t < 12; t++) {
    float2 v = unpackh(pRT[t * NP + pix]);
    rtt[t] = fsilu(fmaf(art, v.x, brt_)) + fsilu(fmaf(att, v.y, btt_));
  }
  float* po = out + (size_t)b * 32 * HW_ + hw;
#pragma unroll
  for (int o = 0; o < 32; o++) {
    float2 mm = unpackh(pMM[o * NP + pix]);
    float tl = bth[o];
#pragma unroll
    for (int t = 0; t < 12; t++) tl = fmaf(wth[o * 12 + t], rtt[t], tl);
    float e = tl + fsilu(fmaf(cf[132 + o], mm.x, cf[164 + o]))
                 + fsilu(fmaf(cf[196 + o], mm.y, cf[228 + o]))
                 + fsilu(fmaf(cf[260 + o], mm.y, cf[292 + o]));
    po[(size_t)o * HW_] = e;
    lenc[o * 264 + tid] = e;
  }
  __syncthreads();
  {
    int o = tid >> 3, j = tid & 7;
    float s = 0, s2 = 0;
#pragma unroll
    for (int k = 0; k < 32; k++) {
      float e = lenc[o * 264 + j + k * 8];
      s += e; s2 = fmaf(e, e, s2);
    }
#pragma unroll
    for (int m = 1; m < 8; m <<= 1) {
      s  += __shfl_xor(s, m, 64);
      s2 += __shfl_xor(s2, m, 64);
    }
    if (j == 0) {
      int sh = blockIdx.x & 3;
      atomicAdd(&dws[EB + ((b * 32 + o) * 2 + 0) * 4 + sh], (double)s);
      atomicAdd(&dws[EB + ((b * 32 + o) * 2 + 1) * 4 + sh], (double)s2);
    }
  }
}

__global__ __launch_bounds__(256) void k_inorm(const double* __restrict__ dws, float* __restrict__ out) {
  int s = blockIdx.y;
  double S = 0, SS = 0;
#pragma unroll
  for (int sh = 0; sh < 4; sh++) {
    S  += dws[EB + (s * 2 + 0) * 4 + sh];
    SS += dws[EB + (s * 2 + 1) * 4 + sh];
  }
  double m = S / 65536.0, v = SS / 65536.0 - m * m;
  float rstd = (float)(1.0 / sqrt(v + 1e-5));
  float mf = (float)m;
  float4* p = (float4*)(out + ((size_t)s << 16));
  int i = blockIdx.x * 256 + threadIdx.x;
  float4 a = p[i];
  a.x = (a.x - mf) * rstd;
  a.y = (a.y - mf) * rstd;
  a.z = (a.z - mf) * rstd;
  a.w = (a.w - mf) * rstd;
  p[i] = a;
}

extern "C" void kernel_launch(void* const* d_in, const int* in_sizes, int n_in,
                              void* d_out, int out_size, void* d_ws, size_t ws_size,
                              hipStream_t stream) {
  const float* x     = (const float*)d_in[0];
  const float* w0    = (const float*)d_in[1];
  const float* g0    = (const float*)d_in[2];
  const float* b0    = (const float*)d_in[3];
  const float* wrt   = (const float*)d_in[4];
  const float* grt   = (const float*)d_in[5];
  const float* brt   = (const float*)d_in[6];
  const float* wtt   = (const float*)d_in[7];
  const float* gtt   = (const float*)d_in[8];
  const float* btt   = (const float*)d_in[9];
  const float* wth   = (const float*)d_in[10];
  const float* bth   = (const float*)d_in[11];
  const float* gmin  = (const float*)d_in[12];
  const float* bmin  = (const float*)d_in[13];
  const float* gmax  = (const float*)d_in[14];
  const float* bmax  = (const float*)d_in[15];
  const float* gmean = (const float*)d_in[16];
  const float* bmean = (const float*)d_in[17];
  double* dws = (double*)d_ws;
  float* cf = (float*)((char*)d_ws + 32768);
  unsigned int* pRT = (unsigned int*)((char*)d_ws + 65536);
  unsigned int* pMM = pRT + 12 * NP;   // needs ws_size >= ~46.3 MB
  float* out = (float*)d_out;

  hipLaunchKernelGGL(k_init, dim3(9), dim3(256), 0, stream, dws);
  hipLaunchKernelGGL(k_xstats, dim3(768), dim3(256), 0, stream, x, dws);
  hipLaunchKernelGGL(k_fin0, dim3(1), dim3(32), 0, stream, dws, w0, g0, b0, cf);
  hipLaunchKernelGGL(k_passB, dim3(1024), dim3(256), 0, stream, x, wrt, wtt, cf, pRT, pMM, dws);
  hipLaunchKernelGGL(k_finB, dim3(1), dim3(64), 0, stream, dws, grt, brt, gtt, btt,
                     gmin, bmin, gmax, bmax, gmean, bmean, cf);
  hipLaunchKernelGGL(k_passC, dim3(1024), dim3(256), 0, stream, pRT, pMM, wth, bth, cf, out, dws);
  hipLaunchKernelGGL(k_inorm, dim3(64, 128), dim3(256), 0, stream, dws, out);
}